// Round 7
// baseline (1086.147 us; speedup 1.0000x reference)
//
#include <hip/hip_runtime.h>
#include <hip/hip_bf16.h>
#include <cstdint>

// MultiHeadAttention w/ sparsemax: B=2, S=2048, D=1024, H=16, DK=64
#define S_LEN  2048
#define DMODEL 1024
#define NHEAD  16
#define M_ROWS 4096                       // B*S
#define CAP    256                        // per-row support-list capacity

typedef __attribute__((ext_vector_type(8))) short bf16x8;   // MFMA A/B frag (8 bf16)
typedef __attribute__((ext_vector_type(4))) float f32x4;    // MFMA C/D frag

__device__ __forceinline__ unsigned short f2bf(float f) {
    __hip_bfloat16 h = __float2bfloat16(f);
    return __builtin_bit_cast(unsigned short, h);
}
__device__ __forceinline__ float bf2f(unsigned short u) {
    return __builtin_bit_cast(float, (unsigned)u << 16);
}
__device__ __forceinline__ uint4 pack8(float4 a, float4 b) {
    uint4 u;
    u.x = ((unsigned)f2bf(a.y) << 16) | f2bf(a.x);
    u.y = ((unsigned)f2bf(a.w) << 16) | f2bf(a.z);
    u.z = ((unsigned)f2bf(b.y) << 16) | f2bf(b.x);
    u.w = ((unsigned)f2bf(b.w) << 16) | f2bf(b.z);
    return u;
}

// ------------------------------------- qkv: C = A@W^T + b (fp32 in, bf16 MFMA)
// Output row-major bf16 [B,S,DMODEL] via LDS-transpose epilogue (16B stores).
__global__ __launch_bounds__(256)
void qkv_gemm(const float* __restrict__ xq, const float* __restrict__ xk,
              const float* __restrict__ xv,
              const float* __restrict__ Wq, const float* __restrict__ Wk,
              const float* __restrict__ Wv,
              const float* __restrict__ bq, const float* __restrict__ bk,
              const float* __restrict__ bv,
              unsigned short* __restrict__ Q_bf, unsigned short* __restrict__ K_bf,
              unsigned short* __restrict__ V_bf) {
    const int which = blockIdx.z;
    const float* A    = (which == 0) ? xq : (which == 1) ? xk : xv;
    const float* W    = (which == 0) ? Wq : (which == 1) ? Wk : Wv;
    const float* bias = (which == 0) ? bq : (which == 1) ? bk : bv;
    unsigned short* dst = (which == 0) ? Q_bf : (which == 1) ? K_bf : V_bf;

    const int row0 = blockIdx.x * 128;
    const int col0 = blockIdx.y * 128;

    __shared__ unsigned short SMEM[10240];    // As(5120)+Bs(5120); epilogue aliases
    unsigned short* As = SMEM;                // stride 40 bf16 (2-way free)
    unsigned short* Bs = SMEM + 5120;

    const int t = threadIdx.x;
    const int wid = t >> 6, lane = t & 63;
    const int wm = wid >> 1, wn = wid & 1;
    const int l = lane & 15, quad = lane >> 4;

    f32x4 acc[4][4];
#pragma unroll
    for (int i = 0; i < 4; ++i)
#pragma unroll
        for (int j = 0; j < 4; ++j) {
            float b_ = bias[col0 + wn * 64 + j * 16 + l];
            acc[i][j] = (f32x4){ b_, b_, b_, b_ };
        }

    for (int k0 = 0; k0 < DMODEL; k0 += 32) {
        uint4 ar[2], br[2];
#pragma unroll
        for (int i = 0; i < 2; ++i) {
            const int c = t + i * 256, r = c >> 2, q = (c & 3) * 8;
            const float* ap = A + (size_t)(row0 + r) * DMODEL + k0 + q;
            const float* wp = W + (size_t)(col0 + r) * DMODEL + k0 + q;
            float4 a0 = *(const float4*)ap, a1 = *(const float4*)(ap + 4);
            float4 w0 = *(const float4*)wp, w1 = *(const float4*)(wp + 4);
            ar[i] = pack8(a0, a1);
            br[i] = pack8(w0, w1);
        }
        __syncthreads();
#pragma unroll
        for (int i = 0; i < 2; ++i) {
            const int c = t + i * 256, r = c >> 2, q = (c & 3) * 8;
            *(uint4*)&As[r * 40 + q] = ar[i];
            *(uint4*)&Bs[r * 40 + q] = br[i];
        }
        __syncthreads();
        bf16x8 a[4], b[4];
#pragma unroll
        for (int i = 0; i < 4; ++i)
            a[i] = *(const bf16x8*)&As[(wm * 64 + i * 16 + l) * 40 + quad * 8];
#pragma unroll
        for (int j = 0; j < 4; ++j)
            b[j] = *(const bf16x8*)&Bs[(wn * 64 + j * 16 + l) * 40 + quad * 8];
#pragma unroll
        for (int i = 0; i < 4; ++i)
#pragma unroll
            for (int j = 0; j < 4; ++j)
                acc[i][j] = __builtin_amdgcn_mfma_f32_16x16x32_bf16(a[i], b[j], acc[i][j], 0, 0, 0);
    }

    __syncthreads();
    unsigned short* Cs = SMEM;                // 128*72 = 9216 <= 10240
#pragma unroll 1
    for (int jh = 0; jh < 2; ++jh) {
        if (wn == jh) {
#pragma unroll
            for (int i = 0; i < 4; ++i)
#pragma unroll
                for (int j = 0; j < 4; ++j)
#pragma unroll
                    for (int r = 0; r < 4; ++r)
                        Cs[(wm * 64 + i * 16 + quad * 4 + r) * 72 + j * 16 + l] =
                            f2bf(acc[i][j][r]);
        }
        __syncthreads();
#pragma unroll
        for (int it = 0; it < 4; ++it) {
            const int idx = t + it * 256;           // 0..1023
            const int row = idx >> 3, c8 = (idx & 7) * 8;
            *(uint4*)(dst + (size_t)(row0 + row) * DMODEL + col0 + jh * 64 + c8) =
                *(const uint4*)&Cs[row * 72 + c8];
        }
        __syncthreads();
    }
}

// --------- fused v2: logits (MFMA) + sparsemax (block-level Newton) + sparse P@V
// grid (128 row-tiles, 32 bh), 512 threads = 8 waves. Wave w: 16 rows x cols
// [w*256, w*256+256) in regs. Newton waterfilling at block level (8 rounds,
// 1 barrier each via parity-buffered stats + per-wave redundant combine).
// Support compacted once with final tau; P written once; PV walks lists.
__global__ __launch_bounds__(512)
void fused_attn2(const unsigned short* __restrict__ Q_bf,
                 const unsigned short* __restrict__ K_bf,
                 const unsigned short* __restrict__ V_bf,
                 float* __restrict__ attn, unsigned short* __restrict__ AO_bf) {
    const int bh = blockIdx.y;
    const int b_ = bh >> 4, h = bh & 15;
    const int m0 = blockIdx.x * 16;
    const unsigned short* Qh = Q_bf + ((size_t)b_ * S_LEN) * DMODEL + h * 64;
    const unsigned short* Kh = K_bf + ((size_t)b_ * S_LEN) * DMODEL + h * 64;
    const unsigned short* Vh = V_bf + ((size_t)b_ * S_LEN) * DMODEL + h * 64;

    __shared__ uint2 list[16][CAP];      // 32 KB: (col, p) support per row
    __shared__ float pstat[2][16][16];   // parity x row x (wave-interleaved s,k)
    __shared__ float pmax[16][8];
    __shared__ int   cnt[16];

    const int t = threadIdx.x;
    const int w = t >> 6, lane = t & 63;
    const int l = lane & 15, quad = lane >> 4;
    const int c0 = w * 256;

    if (t < 16) cnt[t] = 0;

    // ---- A fragments (Q rows m0+l)
    const unsigned short* qr = Qh + (size_t)(m0 + l) * DMODEL;
    bf16x8 a0 = *(const bf16x8*)(qr + quad * 8);
    bf16x8 a1 = *(const bf16x8*)(qr + 32 + quad * 8);

    // ---- S stripe: 16 N-tiles, K=64 (B-frags direct from L2-hot K)
    f32x4 z[16];
#pragma unroll
    for (int nt = 0; nt < 16; ++nt) {
        const unsigned short* kr = Kh + (size_t)(c0 + nt * 16 + l) * DMODEL;
        bf16x8 b0 = *(const bf16x8*)(kr + quad * 8);
        bf16x8 b1 = *(const bf16x8*)(kr + 32 + quad * 8);
        f32x4 acc = { 0.0f, 0.0f, 0.0f, 0.0f };
        acc = __builtin_amdgcn_mfma_f32_16x16x32_bf16(a0, b0, acc, 0, 0, 0);
        acc = __builtin_amdgcn_mfma_f32_16x16x32_bf16(a1, b1, acc, 0, 0, 0);
        z[nt] = acc * 0.125f;
    }
    // z[nt][r] = S[row = quad*4+r][col = c0 + nt*16 + l]

    // ---- row max -> tau0 = m - 1   (1 barrier)
    float tau_r[4];
    {
        float mr[4];
#pragma unroll
        for (int r = 0; r < 4; ++r) {
            float v = z[0][r];
#pragma unroll
            for (int nt = 1; nt < 16; ++nt) v = fmaxf(v, z[nt][r]);
            v = fmaxf(v, __shfl_xor(v, 1, 64));
            v = fmaxf(v, __shfl_xor(v, 2, 64));
            v = fmaxf(v, __shfl_xor(v, 4, 64));
            v = fmaxf(v, __shfl_xor(v, 8, 64));
            mr[r] = v;
        }
        if (l == 0) {
#pragma unroll
            for (int r = 0; r < 4; ++r) pmax[quad * 4 + r][w] = mr[r];
        }
        __syncthreads();
#pragma unroll
        for (int r = 0; r < 4; ++r) {
            const int row = quad * 4 + r;
            float m_ = pmax[row][0];
#pragma unroll
            for (int i = 1; i < 8; ++i) m_ = fmaxf(m_, pmax[row][i]);
            tau_r[r] = m_ - 1.0f;
        }
    }

    // ---- 8 Newton rounds, 1 barrier each (parity double-buffer; every wave's
    //      lanes<16 combine redundantly; wave-local shfl broadcast)
#pragma unroll 1
    for (int it = 0; it < 8; ++it) {
        float s_[4] = {}, k_[4] = {};
#pragma unroll
        for (int nt = 0; nt < 16; ++nt)
#pragma unroll
            for (int r = 0; r < 4; ++r) {
                const float zz = z[nt][r];
                if (zz > tau_r[r]) { s_[r] += zz; k_[r] += 1.0f; }
            }
#pragma unroll
        for (int r = 0; r < 4; ++r) {
            s_[r] += __shfl_xor(s_[r], 1, 64); k_[r] += __shfl_xor(k_[r], 1, 64);
            s_[r] += __shfl_xor(s_[r], 2, 64); k_[r] += __shfl_xor(k_[r], 2, 64);
            s_[r] += __shfl_xor(s_[r], 4, 64); k_[r] += __shfl_xor(k_[r], 4, 64);
            s_[r] += __shfl_xor(s_[r], 8, 64); k_[r] += __shfl_xor(k_[r], 8, 64);
        }
        const int pp = it & 1;
        if (l == 0) {
#pragma unroll
            for (int r = 0; r < 4; ++r) {
                pstat[pp][quad * 4 + r][w * 2 + 0] = s_[r];
                pstat[pp][quad * 4 + r][w * 2 + 1] = k_[r];
            }
        }
        __syncthreads();
        float tau_bc = 0.0f;
        if (lane < 16) {
            const float* ps = pstat[pp][lane];
            float S = 0.0f, K = 0.0f;
#pragma unroll
            for (int i = 0; i < 8; ++i) { S += ps[2 * i]; K += ps[2 * i + 1]; }
            tau_bc = (S - 1.0f) / K;
        }
#pragma unroll
        for (int r = 0; r < 4; ++r) tau_r[r] = __shfl(tau_bc, quad * 4 + r, 64);
    }

    // ---- compact support {z > tau} with exact p = z - tau
#pragma unroll
    for (int nt = 0; nt < 16; ++nt)
#pragma unroll
        for (int r = 0; r < 4; ++r) {
            const float pv = z[nt][r] - tau_r[r];
            if (pv > 0.0f) {
                const int row = quad * 4 + r;
                const int pos = atomicAdd(&cnt[row], 1);
                if (pos < CAP) {
                    uint2 e = { (unsigned)(c0 + nt * 16 + l),
                                __builtin_bit_cast(unsigned, pv) };
                    list[row][pos] = e;
                }
            }
        }

    // ---- P write (the only attention HBM write; required output)
    float* ap = attn + (size_t)bh * S_LEN * S_LEN;
#pragma unroll
    for (int nt = 0; nt < 16; ++nt)
#pragma unroll
        for (int r = 0; r < 4; ++r)
            ap[(size_t)(m0 + quad * 4 + r) * S_LEN + c0 + nt * 16 + l] =
                fmaxf(z[nt][r] - tau_r[r], 0.0f);
    __syncthreads();

    // ---- PV: wave w -> rows 2w, 2w+1; 4 independent V-row loads in flight
#pragma unroll 1
    for (int rr = 0; rr < 2; ++rr) {
        const int row = w * 2 + rr;
        const int n = min(cnt[row], CAP);
        float a = 0.0f;
        int i = 0;
        for (; i + 4 <= n; i += 4) {
            uint2 e0 = list[row][i],     e1 = list[row][i + 1];
            uint2 e2 = list[row][i + 2], e3 = list[row][i + 3];
            float v0 = bf2f(Vh[(size_t)e0.x * DMODEL + lane]);
            float v1 = bf2f(Vh[(size_t)e1.x * DMODEL + lane]);
            float v2 = bf2f(Vh[(size_t)e2.x * DMODEL + lane]);
            float v3 = bf2f(Vh[(size_t)e3.x * DMODEL + lane]);
            a += __builtin_bit_cast(float, e0.y) * v0;
            a += __builtin_bit_cast(float, e1.y) * v1;
            a += __builtin_bit_cast(float, e2.y) * v2;
            a += __builtin_bit_cast(float, e3.y) * v3;
        }
        for (; i < n; ++i) {
            uint2 e0 = list[row][i];
            a += __builtin_bit_cast(float, e0.y) * bf2f(Vh[(size_t)e0.x * DMODEL + lane]);
        }
        const int s = m0 + row;
        AO_bf[((size_t)(b_ * S_LEN + s)) * DMODEL + h * 64 + lane] = f2bf(a);
    }
}

// ---------------------- out = AO @ Wfc^T + bfc (bf16 A, fp32 W inline-cast)
__global__ __launch_bounds__(256)
void fc_gemm(const unsigned short* __restrict__ AO_bf,
             const float* __restrict__ Wfc,
             const float* __restrict__ bfc, float* __restrict__ out) {
    const int row0 = blockIdx.x * 128;
    const int col0 = blockIdx.y * 128;

    __shared__ unsigned short As[128 * 40];
    __shared__ unsigned short Bs[128 * 40];

    const int t = threadIdx.x;
    const int wid = t >> 6, lane = t & 63;
    const int wm = wid >> 1, wn = wid & 1;
    const int l = lane & 15, quad = lane >> 4;

    f32x4 acc[4][4];
#pragma unroll
    for (int i = 0; i < 4; ++i)
#pragma unroll
        for (int j = 0; j < 4; ++j) {
            float b_ = bfc[col0 + wn * 64 + j * 16 + l];
            acc[i][j] = (f32x4){ b_, b_, b_, b_ };
        }

    for (int k0 = 0; k0 < DMODEL; k0 += 32) {
        uint4 ar[2], br[2];
#pragma unroll
        for (int i = 0; i < 2; ++i) {
            const int c = t + i * 256, r = c >> 2, q = (c & 3) * 8;
            ar[i] = *(const uint4*)(AO_bf + (size_t)(row0 + r) * DMODEL + k0 + q);
            const float* wp = Wfc + (size_t)(col0 + r) * DMODEL + k0 + q;
            float4 w0 = *(const float4*)wp, w1 = *(const float4*)(wp + 4);
            br[i] = pack8(w0, w1);
        }
        __syncthreads();
#pragma unroll
        for (int i = 0; i < 2; ++i) {
            const int c = t + i * 256, r = c >> 2, q = (c & 3) * 8;
            *(uint4*)&As[r * 40 + q] = ar[i];
            *(uint4*)&Bs[r * 40 + q] = br[i];
        }
        __syncthreads();
        bf16x8 a[4], b[4];
#pragma unroll
        for (int i = 0; i < 4; ++i)
            a[i] = *(const bf16x8*)&As[(wm * 64 + i * 16 + l) * 40 + quad * 8];
#pragma unroll
        for (int j = 0; j < 4; ++j)
            b[j] = *(const bf16x8*)&Bs[(wn * 64 + j * 16 + l) * 40 + quad * 8];
#pragma unroll
        for (int i = 0; i < 4; ++i)
#pragma unroll
            for (int j = 0; j < 4; ++j)
                acc[i][j] = __builtin_amdgcn_mfma_f32_16x16x32_bf16(a[i], b[j], acc[i][j], 0, 0, 0);
    }

#pragma unroll
    for (int i = 0; i < 4; ++i)
#pragma unroll
        for (int r = 0; r < 4; ++r) {
            const int m = row0 + wm * 64 + i * 16 + quad * 4 + r;
#pragma unroll
            for (int j = 0; j < 4; ++j) {
                const int n = col0 + wn * 64 + j * 16 + l;
                out[(size_t)m * DMODEL + n] = acc[i][j][r];
            }
        }
}

// ----------------------------------------------------------------------- launch
extern "C" void kernel_launch(void* const* d_in, const int* in_sizes, int n_in,
                              void* d_out, int out_size, void* d_ws, size_t ws_size,
                              hipStream_t stream) {
    const float* q   = (const float*)d_in[0];
    const float* k   = (const float*)d_in[1];
    const float* v   = (const float*)d_in[2];
    const float* Wq  = (const float*)d_in[3];
    const float* bq  = (const float*)d_in[4];
    const float* Wk  = (const float*)d_in[5];
    const float* bk  = (const float*)d_in[6];
    const float* Wv  = (const float*)d_in[7];
    const float* bv  = (const float*)d_in[8];
    const float* Wfc = (const float*)d_in[9];
    const float* bfc = (const float*)d_in[10];

    float* out  = (float*)d_out;                       // [B,S,D] fp32
    float* attn = out + (size_t)M_ROWS * DMODEL;       // [B,H,S,S] fp32 (P)

    // workspace: Q_bf [0,8M), K_bf [8,16M), V_bf [16,24M), AO_bf [24,32M)
    char* ws = (char*)d_ws;
    unsigned short* Q_bf  = (unsigned short*)ws;
    unsigned short* K_bf  = (unsigned short*)(ws + (8u << 20));
    unsigned short* V_bf  = (unsigned short*)(ws + (16u << 20));
    unsigned short* AO_bf = (unsigned short*)(ws + (24u << 20));

    qkv_gemm<<<dim3(32, 8, 3), 256, 0, stream>>>(q, k, v, Wq, Wk, Wv,
                                                  bq, bk, bv, Q_bf, K_bf, V_bf);
    fused_attn2<<<dim3(128, 32), 512, 0, stream>>>(Q_bf, K_bf, V_bf, attn, AO_bf);
    fc_gemm<<<dim3(32, 8), 256, 0, stream>>>(AO_bf, Wfc, bfc, out);
}